// Round 8
// baseline (29.557 us; speedup 1.0000x reference)
//
#include <hip/hip_runtime.h>

#define F 32
#define Dd 16
#define C 64
#define Kk 8
#define CLIPV (1.0f - 1e-6f)
#define CHUNKU 264        // ushorts per k-chunk: 32 rows * 8 bf16 + 8 pad -> 528 B (33 16B slots)
#define BUFU (F * CHUNKU) // one 32-row basis buffer: 16896 B
#define K2 2.8853900817779268f  // 2*log2(e): tanh(z)=1-2/(2^(K2*z)+1)
#define NBLK 1024
#define NT 4              // 32-row tiles per block (128 rows/block)

typedef short v8s __attribute__((ext_vector_type(8)));
typedef float v4f __attribute__((ext_vector_type(4)));
typedef float v2f __attribute__((ext_vector_type(2)));

static __device__ inline unsigned cvtpk(float lo, float hi) {
    unsigned r;
    asm("v_cvt_pk_bf16_f32 %0, %1, %2" : "=v"(r) : "v"(lo), "v"(hi));
    return r;
}

// Structure (r8):
//  - feature-major eval, Clenshaw table in VGPRs (r7), 32-row tiles
//  - DOUBLE-BUFFERED basis LDS: one barrier per tile (eval->mfma); the
//    cross-tile WAR hazard (eval t+2 vs mfma t) is ordered by barrier t+1.
//    Global-store drain (vmcnt(0) inside __syncthreads) for tile t happens
//    at barrier t+1, i.e. hidden behind the whole eval of tile t+1.
//  - phase-2 unchanged: wave wu owns classes [16wu,16wu+16), Bfr in VGPRs
__global__ __launch_bounds__(256, 4) void qkan_kernel(
    const float* __restrict__ X,        // [B,32]
    const float* __restrict__ phases,   // [16]
    const float* __restrict__ lcu_w,    // [32,16]
    const float* __restrict__ sscale,   // [32]
    const float* __restrict__ sbias,    // [32]
    const float* __restrict__ coeff,    // [64,32,8]
    const float* __restrict__ kbias,    // [64]
    float* __restrict__ out)            // [B,64]
{
    __shared__ unsigned short s_basis[2 * BUFU];  // 33792 B

    const int tid = threadIdx.x;
    const int lane = tid & 63;
    const int wu = __builtin_amdgcn_readfirstlane(tid >> 6);
    const int h = lane >> 4;
    const int r16 = lane & 15;
    const int fe = tid & 31;   // eval feature
    const int rg = tid >> 5;   // eval row-group (4 rows), 0..7

    const int rb0 = blockIdx.x * (NT * 32);

    // ---- X prefetch for tile 0: xq[m] = X[rb0+rg*4+m][fe] (coalesced) ----
    float xq[4];
    {
        const float* xp = X + (size_t)(rb0 + rg * 4) * F + fe;
#pragma unroll
        for (int m = 0; m < 4; ++m) xq[m] = xp[m * F];
    }

    // ---- fold Clenshaw table for feature fe into VGPRs (once per kernel) ----
    // K2*z(x) = sum_d a_d T_d(x) + sqrt(1-x^2) * sum_d b_d U_{d-1}(x) + fbias
    v2f cc[16];
    float fbias;
    {
        const float* lwf = lcu_w + fe * Dd;
        float wv[16];
        float asum = 0.f;
#pragma unroll
        for (int d = 0; d < Dd; ++d) {
            wv[d] = lwf[d];
            asum += fabsf(wv[d]);
        }
        const float sc = K2 * sscale[fe] / (asum + 1e-6f);
#pragma unroll
        for (int d = 0; d < Dd; ++d) {
            float sp, cp;
            __sincosf(phases[d], &sp, &cp);
            cc[d][0] = sc * wv[d] * cp;    // a_{d+1}
            cc[d][1] = -sc * wv[d] * sp;   // b_{d+1}
        }
        fbias = K2 * sbias[fe];
    }

    // ---- B fragments: wave wu owns classes [16wu,16wu+16) ----
    // MFMA step q, lane quarter h, regs j hold phys kappa=(4q+h)*8+j,
    // i.e. f=4q+h, cheb-k=j (same lane<->k map on A and B => K-perm invariant)
    v8s Bfr[8];
    const int cidx = wu * 16 + r16;
#pragma unroll
    for (int q = 0; q < 8; ++q) {
        const float* gp = coeff + ((size_t)(cidx * F + 4 * q + h) * Kk);
        const float4 g0 = *reinterpret_cast<const float4*>(gp);
        const float4 g1 = *reinterpret_cast<const float4*>(gp + 4);
        union { unsigned u[4]; v8s v; } bb;
        bb.u[0] = cvtpk(g0.x, g0.y);
        bb.u[1] = cvtpk(g0.z, g0.w);
        bb.u[2] = cvtpk(g1.x, g1.y);
        bb.u[3] = cvtpk(g1.z, g1.w);
        Bfr[q] = bb.v;
    }
    const float biasreg = kbias[cidx];

#pragma unroll
    for (int tl = 0; tl < NT; ++tl) {
        const int row_base = rb0 + tl * 32;
        const int buf = (tl & 1) * BUFU;

        // prefetch next tile's X (issued before eval so HBM/L3 latency hides)
        float xn[4];
        if (tl + 1 < NT) {
            const float* xp = X + (size_t)(row_base + 32 + rg * 4) * F + fe;
#pragma unroll
            for (int m = 0; m < 4; ++m) xn[m] = xp[m * F];
        }

        // ---- phase 1: 4 independent row-evals of feature fe, table in VGPRs ----
#pragma unroll
        for (int m = 0; m < 4; ++m) {
            const int row = rg * 4 + m;
            const float x = fminf(fmaxf(xq[m], -CLIPV), CLIPV);
            const float s1 = sqrtf(fmaxf(__builtin_fmaf(-x, x, 1.f), 0.f));
            const float tx = x + x;
            const v2f tx2 = {tx, tx};
            // paired Clenshaw: .x = T-chain (coeff a), .y = U-chain (coeff b)
            v2f w = {0.f, 0.f}, wp = {0.f, 0.f};
#pragma unroll
            for (int j = 15; j >= 0; --j) {
                const v2f wn = (cc[j] - wp) + tx2 * w;  // v_pk_add + v_pk_fma
                wp = w;
                w = wn;
            }
            float z = fbias - wp[0];
            z = __builtin_fmaf(x, w[0], z);
            z = __builtin_fmaf(s1, w[1], z);
            // tanh via exp2 (K2 pre-folded): t = 1 - 2/(2^z + 1)
            float e;
            asm("v_exp_f32 %0, %1" : "=v"(e) : "v"(z));
            const float rr = __builtin_amdgcn_rcpf(e + 1.f);
            const float t = __builtin_fmaf(-2.f, rr, 1.f);
            // Chebyshev basis T_0..T_7 -> one b128 LDS write
            const float t2 = t + t;
            const float b1 = t;
            const float b2 = t2 * b1 - 1.f;
            const float b3 = t2 * b2 - b1;
            const float b4 = t2 * b3 - b2;
            const float b5 = t2 * b4 - b3;
            const float b6 = t2 * b5 - b4;
            const float b7 = t2 * b6 - b5;
            uint4 pk;
            pk.x = cvtpk(1.f, b1);
            pk.y = cvtpk(b2, b3);
            pk.z = cvtpk(b4, b5);
            pk.w = cvtpk(b6, b7);
            *reinterpret_cast<uint4*>(&s_basis[buf + fe * CHUNKU + row * 8]) = pk;
        }
        __syncthreads();  // the ONLY barrier per tile (also drains tile t-1 stores)

        // ---- phase 2: MFMA, wave wu computes classes [16wu,16wu+16) for 32 rows ----
#pragma unroll
        for (int t = 0; t < 2; ++t) {
            v4f acc = {0.f, 0.f, 0.f, 0.f};
#pragma unroll
            for (int q = 0; q < 8; ++q) {
                const v8s a = *reinterpret_cast<const v8s*>(
                    &s_basis[buf + (4 * q + h) * CHUNKU + (t * 16 + r16) * 8]);
                acc = __builtin_amdgcn_mfma_f32_16x16x32_bf16(a, Bfr[q], acc, 0, 0, 0);
            }
            const int row0 = row_base + t * 16 + h * 4;
#pragma unroll
            for (int i = 0; i < 4; ++i) {
                out[(size_t)(row0 + i) * C + cidx] = acc[i] + biasreg;
            }
        }

        if (tl + 1 < NT) {
#pragma unroll
            for (int m = 0; m < 4; ++m) xq[m] = xn[m];
        }
    }
}

extern "C" void kernel_launch(void* const* d_in, const int* in_sizes, int n_in,
                              void* d_out, int out_size, void* d_ws, size_t ws_size,
                              hipStream_t stream) {
    const float* X  = (const float*)d_in[0];
    const float* ph = (const float*)d_in[1];
    const float* lw = (const float*)d_in[2];
    const float* ss = (const float*)d_in[3];
    const float* sb = (const float*)d_in[4];
    const float* kc = (const float*)d_in[5];
    const float* kb = (const float*)d_in[6];
    float* out = (float*)d_out;
    qkan_kernel<<<dim3(NBLK), dim3(256), 0, stream>>>(X, ph, lw, ss, sb, kc, kb, out);
}

// Round 9
// 27.169 us; speedup vs baseline: 1.0879x; 1.0879x over previous
//
#include <hip/hip_runtime.h>

#define F 32
#define Dd 16
#define C 64
#define Kk 8
#define CLIPV (1.0f - 1e-6f)
#define CHUNKU 536        // ushorts per k-chunk: 64 rows * 8 bf16 + pad -> 1072B (67 16B-slots)
#define K2 2.8853900817779268f  // 2*log2(e): tanh(z)=1-2/(2^(K2*z)+1)
#define NBLK 1024
#define MT 2              // row-tiles of 64 per block

typedef short v8s __attribute__((ext_vector_type(8)));
typedef float v4f __attribute__((ext_vector_type(4)));
typedef float v2f __attribute__((ext_vector_type(2)));

static __device__ inline unsigned cvtpk(float lo, float hi) {
    unsigned r;
    asm("v_cvt_pk_bf16_f32 %0, %1, %2" : "=v"(r) : "v"(lo), "v"(hi));
    return r;
}

// LDS-only barriers (the whole point of r9):
// __syncthreads() emits s_waitcnt vmcnt(0) lgkmcnt(0) before s_barrier, which
// drains the in-flight X prefetch and the output stores -- neither is needed
// for the s_basis hazards. BAR_WRITES (after phase-1 ds_writes) waits
// lgkmcnt(0) only; BAR_READS (before overwriting the buffer) needs no wait at
// all: every ds_read of phase-2 was already consumed by an MFMA, so it has
// completed. Memory-clobber fences pin compiler ordering around the barrier.
#define BAR_WRITES() do {                                        \
    asm volatile("s_waitcnt lgkmcnt(0)" ::: "memory");           \
    __builtin_amdgcn_s_barrier();                                \
    asm volatile("" ::: "memory");                               \
} while (0)
#define BAR_READS() do {                                         \
    asm volatile("" ::: "memory");                               \
    __builtin_amdgcn_s_barrier();                                \
    asm volatile("" ::: "memory");                               \
} while (0)

// Structure (r9 = r7 + lazy barriers):
//  - phase-1 feature-major: thread (fe=tid&31, rg=tid>>5) evaluates feature fe
//    for rows rg*8..rg*8+7; folded Clenshaw table (33 coeffs) lives in VGPRs
//    -> zero per-eval table reads, 8 independent chains/thread
//  - phase-2: wave wu owns classes [16wu,16wu+16), Bfr in VGPRs, A-fragments
//    from chunk-major LDS basis (stride 1072B: writes and reads both spread
//    evenly over all 32 banks)
__global__ __launch_bounds__(256, 4) void qkan_kernel(
    const float* __restrict__ X,        // [B,32]
    const float* __restrict__ phases,   // [16]
    const float* __restrict__ lcu_w,    // [32,16]
    const float* __restrict__ sscale,   // [32]
    const float* __restrict__ sbias,    // [32]
    const float* __restrict__ coeff,    // [64,32,8]
    const float* __restrict__ kbias,    // [64]
    float* __restrict__ out)            // [B,64]
{
    __shared__ unsigned short s_basis[F * CHUNKU];   // 34304 B

    const int tid = threadIdx.x;
    const int lane = tid & 63;
    const int wu = __builtin_amdgcn_readfirstlane(tid >> 6);
    const int h = lane >> 4;
    const int r16 = lane & 15;
    const int fe = tid & 31;   // eval feature
    const int rg = tid >> 5;   // eval row-group (8 rows)

    const int rb0 = blockIdx.x * (MT * 64);

    // ---- X prefetch for tile 0: xq[m] = X[rb0+rg*8+m][fe] (coalesced) ----
    float xq[8];
    {
        const float* xp = X + (size_t)(rb0 + rg * 8) * F + fe;
#pragma unroll
        for (int m = 0; m < 8; ++m) xq[m] = xp[m * F];
    }

    // ---- fold Clenshaw table for feature fe into VGPRs (once per kernel) ----
    // K2*z(x) = sum_d a_d T_d(x) + sqrt(1-x^2) * sum_d b_d U_{d-1}(x) + fbias
    v2f cc[16];
    float fbias;
    {
        const float* lwf = lcu_w + fe * Dd;
        float wv[16];
        float asum = 0.f;
#pragma unroll
        for (int d = 0; d < Dd; ++d) {
            wv[d] = lwf[d];
            asum += fabsf(wv[d]);
        }
        const float sc = K2 * sscale[fe] / (asum + 1e-6f);
#pragma unroll
        for (int d = 0; d < Dd; ++d) {
            float sp, cp;
            __sincosf(phases[d], &sp, &cp);
            cc[d][0] = sc * wv[d] * cp;    // a_{d+1}
            cc[d][1] = -sc * wv[d] * sp;   // b_{d+1}
        }
        fbias = K2 * sbias[fe];
    }

    // ---- B fragments: wave wu owns classes [16wu,16wu+16) ----
    // MFMA step q, lane quarter h, regs j hold phys kappa=(4q+h)*8+j,
    // i.e. f=4q+h, cheb-k=j (same lane<->k map on A and B => K-perm invariant)
    v8s Bfr[8];
    const int cidx = wu * 16 + r16;
#pragma unroll
    for (int q = 0; q < 8; ++q) {
        const float* gp = coeff + ((size_t)(cidx * F + 4 * q + h) * Kk);
        const float4 g0 = *reinterpret_cast<const float4*>(gp);
        const float4 g1 = *reinterpret_cast<const float4*>(gp + 4);
        union { unsigned u[4]; v8s v; } bb;
        bb.u[0] = cvtpk(g0.x, g0.y);
        bb.u[1] = cvtpk(g0.z, g0.w);
        bb.u[2] = cvtpk(g1.x, g1.y);
        bb.u[3] = cvtpk(g1.z, g1.w);
        Bfr[q] = bb.v;
    }
    const float biasreg = kbias[cidx];

    for (int mt = 0; mt < MT; ++mt) {
        const int row_base = rb0 + mt * 64;
        if (mt) BAR_READS();  // prev phase-2 LDS reads all consumed; no VMEM drain

        // prefetch next tile's X (stays in flight across the barriers now)
        float xn[8];
        if (mt + 1 < MT) {
            const float* xp = X + (size_t)(row_base + 64 + rg * 8) * F + fe;
#pragma unroll
            for (int m = 0; m < 8; ++m) xn[m] = xp[m * F];
        }

        // ---- phase 1: 8 independent row-evals of feature fe, table in VGPRs ----
#pragma unroll
        for (int m = 0; m < 8; ++m) {
            const int row = rg * 8 + m;
            const float x = fminf(fmaxf(xq[m], -CLIPV), CLIPV);
            const float s1 = sqrtf(fmaxf(__builtin_fmaf(-x, x, 1.f), 0.f));
            const float tx = x + x;
            const v2f tx2 = {tx, tx};
            // paired Clenshaw: .x = T-chain (coeff a), .y = U-chain (coeff b)
            v2f w = {0.f, 0.f}, wp = {0.f, 0.f};
#pragma unroll
            for (int j = 15; j >= 0; --j) {
                const v2f wn = (cc[j] - wp) + tx2 * w;  // v_pk_add + v_pk_fma
                wp = w;
                w = wn;
            }
            float z = fbias - wp[0];
            z = __builtin_fmaf(x, w[0], z);
            z = __builtin_fmaf(s1, w[1], z);
            // tanh via exp2 (K2 pre-folded): t = 1 - 2/(2^z + 1)
            float e;
            asm("v_exp_f32 %0, %1" : "=v"(e) : "v"(z));
            const float rr = __builtin_amdgcn_rcpf(e + 1.f);
            const float t = __builtin_fmaf(-2.f, rr, 1.f);
            // Chebyshev basis T_0..T_7 -> one b128 LDS write
            const float t2 = t + t;
            const float b1 = t;
            const float b2 = t2 * b1 - 1.f;
            const float b3 = t2 * b2 - b1;
            const float b4 = t2 * b3 - b2;
            const float b5 = t2 * b4 - b3;
            const float b6 = t2 * b5 - b4;
            const float b7 = t2 * b6 - b5;
            uint4 pk;
            pk.x = cvtpk(1.f, b1);
            pk.y = cvtpk(b2, b3);
            pk.z = cvtpk(b4, b5);
            pk.w = cvtpk(b6, b7);
            *reinterpret_cast<uint4*>(&s_basis[fe * CHUNKU + row * 8]) = pk;
        }
        BAR_WRITES();  // lgkmcnt(0) only: writes visible; X/stores stay in flight

        // ---- phase 2: MFMA, wave wu computes classes [16wu,16wu+16) for 64 rows ----
#pragma unroll
        for (int t = 0; t < 4; ++t) {
            v4f acc = {0.f, 0.f, 0.f, 0.f};
#pragma unroll
            for (int q = 0; q < 8; ++q) {
                const v8s a = *reinterpret_cast<const v8s*>(
                    &s_basis[(4 * q + h) * CHUNKU + (t * 16 + r16) * 8]);
                acc = __builtin_amdgcn_mfma_f32_16x16x32_bf16(a, Bfr[q], acc, 0, 0, 0);
            }
            const int row0 = row_base + t * 16 + h * 4;
#pragma unroll
            for (int i = 0; i < 4; ++i) {
                out[(size_t)(row0 + i) * C + cidx] = acc[i] + biasreg;
            }
        }

        if (mt + 1 < MT) {
#pragma unroll
            for (int m = 0; m < 8; ++m) xq[m] = xn[m];
        }
    }
}

extern "C" void kernel_launch(void* const* d_in, const int* in_sizes, int n_in,
                              void* d_out, int out_size, void* d_ws, size_t ws_size,
                              hipStream_t stream) {
    const float* X  = (const float*)d_in[0];
    const float* ph = (const float*)d_in[1];
    const float* lw = (const float*)d_in[2];
    const float* ss = (const float*)d_in[3];
    const float* sb = (const float*)d_in[4];
    const float* kc = (const float*)d_in[5];
    const float* kb = (const float*)d_in[6];
    float* out = (float*)d_out;
    qkan_kernel<<<dim3(NBLK), dim3(256), 0, stream>>>(X, ph, lw, ss, sb, kc, kb, out);
}